// Round 11
// baseline (161.678 us; speedup 1.0000x reference)
//
#include <hip/hip_runtime.h>
#include <hip/hip_bf16.h>
#include <math.h>

#define B_SZ 16
#define L_SEQ 128
#define D_M 32
#define HW 65536           // 256*256
#define NROWS (B_SZ * 128) // 2048 (b,c) rows
#define NCHUNK 2           // chunks per row for kmax

typedef float vfloat4 __attribute__((ext_vector_type(4)));

// Device-global scratch
__device__ float g_part[NROWS * NCHUNK];            // partial maxima
__device__ float g_y[2][B_SZ * L_SEQ * D_M];        // per-dir y, [b][l][d], fwd orientation
__device__ int   g_done[B_SZ];                      // arrival counters (self-resetting)

__device__ __forceinline__ float silu_acc(float x) {
    return x / (1.f + __expf(-x));
}
__device__ __forceinline__ float softplusf(float x) {
    return (x > 20.f) ? x : log1pf(__expf(x));
}

__device__ __forceinline__ float row_max(int row) {
    const int r2 = row * NCHUNK;
    return fmaxf(g_part[r2], g_part[r2 + 1]);
}

// h[0..31] = LN(s*w1+b1), in registers; weights via uniform scalar loads.
__device__ __forceinline__ void compute_h(int row, const float* __restrict__ w1,
                                          const float* __restrict__ b1,
                                          const float* __restrict__ lng,
                                          const float* __restrict__ lnb,
                                          float h[D_M]) {
    const float s = row_max(row);
    float mean = 0.f;
#pragma unroll
    for (int d = 0; d < D_M; d++) { h[d] = s * w1[d] + b1[d]; mean += h[d]; }
    mean *= (1.f / D_M);
    float var = 0.f;
#pragma unroll
    for (int d = 0; d < D_M; d++) { float t = h[d] - mean; var += t * t; }
    var *= (1.f / D_M);
    const float rs = rsqrtf(var + 1e-5f);
#pragma unroll
    for (int d = 0; d < D_M; d++) h[d] = (h[d] - mean) * rs * lng[d] + lnb[d];
}

// ---------------- K1: partial max over half-rows (R7 verbatim, NT loads) ----------------
__global__ __launch_bounds__(256) void kmax(const float* __restrict__ x) {
    const int blk = blockIdx.x;                 // 0..4095
    const vfloat4* __restrict__ p =
        reinterpret_cast<const vfloat4*>(x) + (size_t)blk * 8192;
    const int t = threadIdx.x;
    float m0 = -INFINITY, m1 = -INFINITY, m2 = -INFINITY, m3 = -INFINITY;
#pragma unroll
    for (int i = 0; i < 8192; i += 1024) {
        vfloat4 v0 = __builtin_nontemporal_load(p + i + t);
        vfloat4 v1 = __builtin_nontemporal_load(p + i + t + 256);
        vfloat4 v2 = __builtin_nontemporal_load(p + i + t + 512);
        vfloat4 v3 = __builtin_nontemporal_load(p + i + t + 768);
        m0 = fmaxf(m0, fmaxf(fmaxf(v0.x, v0.y), fmaxf(v0.z, v0.w)));
        m1 = fmaxf(m1, fmaxf(fmaxf(v1.x, v1.y), fmaxf(v1.z, v1.w)));
        m2 = fmaxf(m2, fmaxf(fmaxf(v2.x, v2.y), fmaxf(v2.z, v2.w)));
        m3 = fmaxf(m3, fmaxf(fmaxf(v3.x, v3.y), fmaxf(v3.z, v3.w)));
    }
    float m = fmaxf(fmaxf(m0, m1), fmaxf(m2, m3));
#pragma unroll
    for (int off = 32; off >= 1; off >>= 1)
        m = fmaxf(m, __shfl_xor(m, off));
    __shared__ float sm[4];
    if ((threadIdx.x & 63) == 0) sm[threadIdx.x >> 6] = m;
    __syncthreads();
    if (threadIdx.x == 0)
        g_part[blk] = fmaxf(fmaxf(sm[0], sm[1]), fmaxf(sm[2], sm[3]));
}

// ---------------- K2: per (batch, direction), 1024 threads, 5-phase tail ----------------
// LDS word map (~46.5 KB):
//  [0,4352)      sx  [32][136] front pad 4 (zeros), data +4
//  [4352,8576)   su  [32][132]
//  [8576,8832)   sdt [128][2]
//  [8832,9984)   sB  [128][9]
//  [9984,11136)  sC  [128][9]
__global__ __launch_bounds__(1024) void ktail(
    const float* __restrict__ w1,  const float* __restrict__ b1,
    const float* __restrict__ lng, const float* __restrict__ lnb,
    const float* __restrict__ Win,
    const float* __restrict__ cw_f, const float* __restrict__ cb_f,
    const float* __restrict__ xp_f, const float* __restrict__ dtw_f,
    const float* __restrict__ dtb_f, const float* __restrict__ Al_f,
    const float* __restrict__ Dp_f,
    const float* __restrict__ cw_b, const float* __restrict__ cb_b,
    const float* __restrict__ xp_b, const float* __restrict__ dtw_b,
    const float* __restrict__ dtb_b, const float* __restrict__ Al_b,
    const float* __restrict__ Dp_b,
    const float* __restrict__ ng,  const float* __restrict__ nb,
    const float* __restrict__ Wout, const float* __restrict__ w2,
    const float* __restrict__ b2,  float* __restrict__ out) {
    const int b   = blockIdx.x >> 1;
    const int dir = blockIdx.x & 1;
    const int tid = threadIdx.x;

    const float* cw  = dir ? cw_b  : cw_f;
    const float* cb  = dir ? cb_b  : cb_f;
    const float* xp  = dir ? xp_b  : xp_f;
    const float* dtw = dir ? dtw_b : dtw_f;
    const float* dtb = dir ? dtb_b : dtb_f;
    const float* Al  = dir ? Al_b  : Al_f;
    const float* Dp  = dir ? Dp_b  : Dp_f;

    __shared__ __align__(16) float S[11136];
    __shared__ int s_flag;
    float* sx  = S;            // [32][136], data at +4
    float* su  = S + 4352;     // [32][132]
    float* sdt = S + 8576;     // [128][2]
    float* sB  = S + 8832;     // [128][9]
    float* sC  = S + 9984;     // [128][9]

    const int l = tid & 127;
    const int q = tid >> 7;    // 0..7 (wave-uniform)

    // ---- Phase 1+2: conv front-pad zeros; h in regs; x-half GEMV pre-flipped ----
    if (tid < 128) sx[(tid >> 2) * 136 + (tid & 3)] = 0.f;
    float h[D_M];
    compute_h(b * L_SEQ + l, w1, b1, lng, lnb, h);
    {
        const int lw = dir ? (127 - l) : l;
        const int qq = __builtin_amdgcn_readfirstlane(q);
#pragma unroll
        for (int k = 0; k < 4; k++) {
            const int e = qq * 4 + k;          // wave-uniform -> scalar loads
            float acc = 0.f;
#pragma unroll
            for (int d = 0; d < D_M; d++) acc += h[d] * Win[e * 32 + d];
            sx[e * 136 + 4 + lw] = acc;
        }
    }
    __syncthreads();

    // ---- Phase 3: causal conv(4) + SiLU ----
    {
        const int d  = tid >> 5;          // 0..31
        const int l0 = (tid & 31) * 4;    // 0,4,...,124
        const vfloat4* px = reinterpret_cast<const vfloat4*>(sx + d * 136 + l0);
        vfloat4 a0 = px[0], a1 = px[1];   // l0-4..l0-1, l0..l0+3
        float xv[7] = {a0.y, a0.z, a0.w, a1.x, a1.y, a1.z, a1.w};
        const float c0 = cw[d*4+0], c1 = cw[d*4+1], c2 = cw[d*4+2], c3 = cw[d*4+3];
        const float cbd = cb[d];
        float uo[4];
#pragma unroll
        for (int j = 0; j < 4; j++) {
            float acc = cbd + c0*xv[j] + c1*xv[j+1] + c2*xv[j+2] + c3*xv[j+3];
            uo[j] = silu_acc(acc);
        }
        vfloat4 u0 = {uo[0], uo[1], uo[2], uo[3]};
        *reinterpret_cast<vfloat4*>(su + d * 132 + l0) = u0;
    }
    __syncthreads();

    // ---- Phase 4: x_dbl = u^T @ xp^T -> sdt, sB, sC ----
    {
        float ul[D_M];
#pragma unroll
        for (int d = 0; d < D_M; d++) ul[d] = su[d * 132 + l];
        const int qq = __builtin_amdgcn_readfirstlane(q);
#pragma unroll
        for (int rep = 0; rep < 3; rep++) {
            const int r = qq + rep * 8;        // wave-uniform -> scalar loads
            if (rep == 2 && qq >= 2) break;
            float acc = 0.f;
#pragma unroll
            for (int d = 0; d < D_M; d++) acc += ul[d] * xp[r * 32 + d];
            if (r < 2)       sdt[l * 2 + r] = acc;
            else if (r < 10) sB[l * 9 + (r - 2)] = acc;
            else             sC[l * 9 + (r - 10)] = acc;
        }
    }
    __syncthreads();

    // ---- Phase 5: chunked scan, delta folded in, y -> global directly ----
    {
        const int d = tid >> 5;
        const int n = (tid >> 2) & 7;
        const int c = tid & 3;
        const float A   = -__expf(Al[d * 8 + n]);
        const float Dd  = Dp[d];
        const float dw0 = dtw[d * 2 + 0], dw1 = dtw[d * 2 + 1], db = dtb[d];
        const int lbase = c * 32;

        // Pass 1: chunk-local affine composition (Ac, Wc)
        float Ac = 1.f, Wc = 0.f;
        for (int i = 0; i < 32; i++) {
            const int ll = lbase + i;
            const float dl = softplusf(sdt[ll*2+0]*dw0 + sdt[ll*2+1]*dw1 + db);
            const float ul = su[d * 132 + ll];
            const float w  = (dl * ul) * sB[ll * 9 + n];
            const float dA = __expf(dl * A);
            Wc = dA * Wc + w;
            Ac *= dA;
        }
        // Exclusive prefix over the 4 chunks (lanes 4m..4m+3 share (d,n))
        float h0 = 0.f;
#pragma unroll
        for (int j = 0; j < 3; j++) {
            const float Aj = __shfl(Ac, j, 4);
            const float Wj = __shfl(Wc, j, 4);
            if (j < c) h0 = Aj * h0 + Wj;
        }
        // Pass 2: rescan from h0, write y straight to g_y[b][l][d] (fwd orient.)
        float* gyd = &g_y[dir][(size_t)b * L_SEQ * D_M];
        float hst = h0;
        for (int i = 0; i < 32; i++) {
            const int ll = lbase + i;
            const float dl = softplusf(sdt[ll*2+0]*dw0 + sdt[ll*2+1]*dw1 + db);
            const float ul = su[d * 132 + ll];
            const float dA = __expf(dl * A);
            hst = dA * hst + (dl * ul) * sB[ll * 9 + n];
            float y = hst * sC[ll * 9 + n];
            y += __shfl_xor(y, 4);
            y += __shfl_xor(y, 8);
            y += __shfl_xor(y, 16);
            if (n == 0) {
                const int gl = dir ? (127 - ll) : ll;
                gyd[gl * D_M + d] = y + Dd * ul;
            }
        }
    }
    __syncthreads();

    // ---- Arrival: last block of this batch runs the final stage ----
    if (tid == 0) {
        __threadfence();
        const int old = atomicAdd(&g_done[b], 1);
        const int win = (old == 1);
        if (win) {
            atomicExch(&g_done[b], 0);
            __threadfence();
        }
        s_flag = win;
    }
    __syncthreads();
    if (!s_flag) return;

    // ---- Final (winner, tid<128): z GEMV + combine + LN/2 + out_proj ----
    if (tid < 128) {
        const vfloat4* y0 = reinterpret_cast<const vfloat4*>(
            &g_y[0][((size_t)b * L_SEQ + l) * D_M]);
        const vfloat4* y1 = reinterpret_cast<const vfloat4*>(
            &g_y[1][((size_t)b * L_SEQ + l) * D_M]);
        float v[D_M];
#pragma unroll
        for (int dv = 0; dv < 8; dv++) {
            const vfloat4 a = y0[dv], bb = y1[dv];
#pragma unroll
            for (int j = 0; j < 4; j++) {
                const int d = dv * 4 + j;
                float z = 0.f;
#pragma unroll
                for (int k = 0; k < D_M; k++) z += h[k] * Win[(32 + d) * 32 + k];
                const float yc = ((const float*)&a)[j] + ((const float*)&bb)[j];
                v[d] = yc * silu_acc(z);
            }
        }
        float mean = 0.f;
#pragma unroll
        for (int d = 0; d < D_M; d++) mean += v[d];
        mean *= (1.f / D_M);
        float var = 0.f;
#pragma unroll
        for (int d = 0; d < D_M; d++) { float t = v[d] - mean; var += t * t; }
        var *= (1.f / D_M);
        const float rs = rsqrtf(var + 1e-5f);
#pragma unroll
        for (int d = 0; d < D_M; d++)
            v[d] = ((v[d] - mean) * rs * ng[d] + nb[d]) * 0.5f;

        float acc = 0.f;
        for (int o = 0; o < D_M; o++) {
            float t = 0.f;
#pragma unroll
            for (int d = 0; d < D_M; d++) t += v[d] * Wout[o * 32 + d];
            acc += t * w2[o];
        }
        acc += b2[0];
        out[b * L_SEQ + l] = 1.f / (1.f + __expf(-acc));
    }
}

extern "C" void kernel_launch(void* const* d_in, const int* in_sizes, int n_in,
                              void* d_out, int out_size, void* d_ws, size_t ws_size,
                              hipStream_t stream) {
    const float* x        = (const float*)d_in[0];
    const float* w1       = (const float*)d_in[1];
    const float* b1       = (const float*)d_in[2];
    const float* ln_g     = (const float*)d_in[3];
    const float* ln_b     = (const float*)d_in[4];
    const float* in_proj  = (const float*)d_in[5];
    const float* cw_f     = (const float*)d_in[6];
    const float* cb_f     = (const float*)d_in[7];
    const float* xp_f     = (const float*)d_in[8];
    const float* dtw_f    = (const float*)d_in[9];
    const float* dtb_f    = (const float*)d_in[10];
    const float* Al_f     = (const float*)d_in[11];
    const float* Dp_f     = (const float*)d_in[12];
    const float* cw_b     = (const float*)d_in[13];
    const float* cb_b     = (const float*)d_in[14];
    const float* xp_b     = (const float*)d_in[15];
    const float* dtw_b    = (const float*)d_in[16];
    const float* dtb_b    = (const float*)d_in[17];
    const float* Al_b     = (const float*)d_in[18];
    const float* Dp_b     = (const float*)d_in[19];
    const float* norm_g   = (const float*)d_in[20];
    const float* norm_b   = (const float*)d_in[21];
    const float* Wout     = (const float*)d_in[22];
    const float* w2       = (const float*)d_in[23];
    const float* b2       = (const float*)d_in[24];

    kmax<<<NROWS * NCHUNK, 256, 0, stream>>>(x);
    ktail<<<B_SZ * 2, 1024, 0, stream>>>(w1, b1, ln_g, ln_b, in_proj,
                                         cw_f, cb_f, xp_f, dtw_f, dtb_f, Al_f, Dp_f,
                                         cw_b, cb_b, xp_b, dtw_b, dtb_b, Al_b, Dp_b,
                                         norm_g, norm_b, Wout, w2, b2, (float*)d_out);
}

// Round 12
// 112.977 us; speedup vs baseline: 1.4311x; 1.4311x over previous
//
#include <hip/hip_runtime.h>
#include <hip/hip_bf16.h>
#include <math.h>

#define B_SZ 16
#define L_SEQ 128
#define D_M 32
#define HW 65536           // 256*256
#define NROWS (B_SZ * 128) // 2048 (b,c) rows
#define NCHUNK 2           // chunks per row for kmax

typedef float vfloat4 __attribute__((ext_vector_type(4)));

// Device-global scratch
__device__ float g_part[NROWS * NCHUNK];          // partial maxima
__device__ float g_y[2][B_SZ * D_M * L_SEQ];      // per-dir y, [b][d][l], fwd orientation
__device__ int   g_done[B_SZ];                    // arrival counters (self-resetting)

__device__ __forceinline__ float silu_acc(float x) {
    return x / (1.f + __expf(-x));
}
__device__ __forceinline__ float softplusf(float x) {
    return (x > 20.f) ? x : log1pf(__expf(x));
}

__device__ __forceinline__ float row_max(int row) {
    const int r2 = row * NCHUNK;
    return fmaxf(g_part[r2], g_part[r2 + 1]);
}

// h[0..31] = LN(s*w1+b1), in registers; weights via uniform scalar loads.
__device__ __forceinline__ void compute_h(int row, const float* __restrict__ w1,
                                          const float* __restrict__ b1,
                                          const float* __restrict__ lng,
                                          const float* __restrict__ lnb,
                                          float h[D_M]) {
    const float s = row_max(row);
    float mean = 0.f;
#pragma unroll
    for (int d = 0; d < D_M; d++) { h[d] = s * w1[d] + b1[d]; mean += h[d]; }
    mean *= (1.f / D_M);
    float var = 0.f;
#pragma unroll
    for (int d = 0; d < D_M; d++) { float t = h[d] - mean; var += t * t; }
    var *= (1.f / D_M);
    const float rs = rsqrtf(var + 1e-5f);
#pragma unroll
    for (int d = 0; d < D_M; d++) h[d] = (h[d] - mean) * rs * lng[d] + lnb[d];
}

// ---------------- K1: partial max over half-rows (R7 verbatim, NT loads) ----------------
__global__ __launch_bounds__(256) void kmax(const float* __restrict__ x) {
    const int blk = blockIdx.x;                 // 0..4095
    const vfloat4* __restrict__ p =
        reinterpret_cast<const vfloat4*>(x) + (size_t)blk * 8192;
    const int t = threadIdx.x;
    float m0 = -INFINITY, m1 = -INFINITY, m2 = -INFINITY, m3 = -INFINITY;
#pragma unroll
    for (int i = 0; i < 8192; i += 1024) {
        vfloat4 v0 = __builtin_nontemporal_load(p + i + t);
        vfloat4 v1 = __builtin_nontemporal_load(p + i + t + 256);
        vfloat4 v2 = __builtin_nontemporal_load(p + i + t + 512);
        vfloat4 v3 = __builtin_nontemporal_load(p + i + t + 768);
        m0 = fmaxf(m0, fmaxf(fmaxf(v0.x, v0.y), fmaxf(v0.z, v0.w)));
        m1 = fmaxf(m1, fmaxf(fmaxf(v1.x, v1.y), fmaxf(v1.z, v1.w)));
        m2 = fmaxf(m2, fmaxf(fmaxf(v2.x, v2.y), fmaxf(v2.z, v2.w)));
        m3 = fmaxf(m3, fmaxf(fmaxf(v3.x, v3.y), fmaxf(v3.z, v3.w)));
    }
    float m = fmaxf(fmaxf(m0, m1), fmaxf(m2, m3));
#pragma unroll
    for (int off = 32; off >= 1; off >>= 1)
        m = fmaxf(m, __shfl_xor(m, off));
    __shared__ float sm[4];
    if ((threadIdx.x & 63) == 0) sm[threadIdx.x >> 6] = m;
    __syncthreads();
    if (threadIdx.x == 0)
        g_part[blk] = fmaxf(fmaxf(sm[0], sm[1]), fmaxf(sm[2], sm[3]));
}

// ---------------- K2: per (batch, direction), 1024 threads (R10 base + parallel final) ----------------
// LDS word map (15360 = 61.4 KB):
//  [0,4352)      sx  [32][136] pad4 / sdl overlay [128][33] / sv overlay [128][33] (final)
//  [4352,8576)   su  [32][132]           / sp overlay [8][128] (final)
//  [8576,12800)  sy  [32][132]
//  [12800,13056) sdt [128][2]
//  [13056,14208) sB  [128][9]
//  [14208,15360) sC  [128][9]
__global__ __launch_bounds__(1024) void ktail(
    const float* __restrict__ w1,  const float* __restrict__ b1,
    const float* __restrict__ lng, const float* __restrict__ lnb,
    const float* __restrict__ Win,
    const float* __restrict__ cw_f, const float* __restrict__ cb_f,
    const float* __restrict__ xp_f, const float* __restrict__ dtw_f,
    const float* __restrict__ dtb_f, const float* __restrict__ Al_f,
    const float* __restrict__ Dp_f,
    const float* __restrict__ cw_b, const float* __restrict__ cb_b,
    const float* __restrict__ xp_b, const float* __restrict__ dtw_b,
    const float* __restrict__ dtb_b, const float* __restrict__ Al_b,
    const float* __restrict__ Dp_b,
    const float* __restrict__ ng,  const float* __restrict__ nb,
    const float* __restrict__ Wout, const float* __restrict__ w2,
    const float* __restrict__ b2,  float* __restrict__ out) {
    const int b   = blockIdx.x >> 1;
    const int dir = blockIdx.x & 1;
    const int tid = threadIdx.x;

    const float* cw  = dir ? cw_b  : cw_f;
    const float* cb  = dir ? cb_b  : cb_f;
    const float* xp  = dir ? xp_b  : xp_f;
    const float* dtw = dir ? dtw_b : dtw_f;
    const float* dtb = dir ? dtb_b : dtb_f;
    const float* Al  = dir ? Al_b  : Al_f;
    const float* Dp  = dir ? Dp_b  : Dp_f;

    __shared__ __align__(16) float S[15360];
    __shared__ int s_flag;
    float* sx  = S;            // [32][136], data at +4
    float* sdl = S;            // [128][33] overlay (after conv consumed sx)
    float* su  = S + 4352;     // [32][132]
    float* sy  = S + 8576;     // [32][132]
    float* sdt = S + 12800;    // [128][2]
    float* sB  = S + 13056;    // [128][9]
    float* sC  = S + 14208;    // [128][9]

    const int l = tid & 127;
    const int q = tid >> 7;    // 0..7 (wave-uniform)
    const int qq = __builtin_amdgcn_readfirstlane(q);

    // Phase 1: zero conv front-pad; h in registers (8x redundant per l)
    if (tid < 128) sx[(tid >> 2) * 136 + (tid & 3)] = 0.f;
    float h[D_M];
    compute_h(b * L_SEQ + l, w1, b1, lng, lnb, h);

    // Phase 2: x-half GEMV (scalar-load weights), stored pre-flipped; 4 rows/thread
    {
        const int lw = dir ? (127 - l) : l;
#pragma unroll
        for (int k = 0; k < 4; k++) {
            const int e = qq * 4 + k;
            float acc = 0.f;
#pragma unroll
            for (int d = 0; d < D_M; d++) acc += h[d] * Win[e * 32 + d];
            sx[e * 136 + 4 + lw] = acc;
        }
    }

    // z pre-compute (pre-arrival, both blocks; depends only on h): zs[k] = silu(z[qq*4+k])
    float zs[4];
#pragma unroll
    for (int k = 0; k < 4; k++) {
        const int d = qq * 4 + k;
        float z = 0.f;
#pragma unroll
        for (int kk = 0; kk < D_M; kk++) z += h[kk] * Win[(32 + d) * 32 + kk];
        zs[k] = silu_acc(z);
    }
    __syncthreads();

    // Phase 3: causal conv(4) + SiLU; thread = (d, 4-l block)
    {
        const int d  = tid >> 5;          // 0..31
        const int l0 = (tid & 31) * 4;    // 0,4,...,124
        const vfloat4* px = reinterpret_cast<const vfloat4*>(sx + d * 136 + l0);
        vfloat4 a0 = px[0], a1 = px[1];   // data l0-4..l0-1, l0..l0+3
        float xv[7] = {a0.y, a0.z, a0.w, a1.x, a1.y, a1.z, a1.w};
        const float c0 = cw[d*4+0], c1 = cw[d*4+1], c2 = cw[d*4+2], c3 = cw[d*4+3];
        const float cbd = cb[d];
        float uo[4];
#pragma unroll
        for (int j = 0; j < 4; j++) {
            float acc = cbd + c0*xv[j] + c1*xv[j+1] + c2*xv[j+2] + c3*xv[j+3];
            uo[j] = silu_acc(acc);
        }
        vfloat4 u0 = {uo[0], uo[1], uo[2], uo[3]};
        *reinterpret_cast<vfloat4*>(su + d * 132 + l0) = u0;
    }
    __syncthreads();

    // Phase 4: x_dbl = u^T @ xp^T; rows r = qq, qq+8, (qq<2: qq+16)
    {
        float ul[D_M];
#pragma unroll
        for (int d = 0; d < D_M; d++) ul[d] = su[d * 132 + l];
#pragma unroll
        for (int rep = 0; rep < 3; rep++) {
            const int r = qq + rep * 8;
            if (rep == 2 && qq >= 2) break;
            float acc = 0.f;
#pragma unroll
            for (int d = 0; d < D_M; d++) acc += ul[d] * xp[r * 32 + d];
            if (r < 2)       sdt[l * 2 + r] = acc;
            else if (r < 10) sB[l * 9 + (r - 2)] = acc;
            else             sC[l * 9 + (r - 10)] = acc;
        }
    }
    __syncthreads();

    // Phase 5: delta = softplus(dt @ dtw^T + dtb), overlays sx; 4 d's/thread
    {
        const float dt0 = sdt[l * 2 + 0], dt1 = sdt[l * 2 + 1];
        const int d0 = qq * 4;
#pragma unroll
        for (int j = 0; j < 4; j++) {
            const int d = d0 + j;
            const float t = dt0 * dtw[d * 2 + 0] + dt1 * dtw[d * 2 + 1] + dtb[d];
            sdl[l * 33 + d] = softplusf(t);
        }
    }
    __syncthreads();

    // Phase 6: chunked parallel scan. thread = (d, n, c): 32*8*4 = 1024.
    {
        const int d = tid >> 5;
        const int n = (tid >> 2) & 7;
        const int c = tid & 3;
        const float A  = -__expf(Al[d * 8 + n]);
        const float Dd = Dp[d];
        const int lbase = c * 32;

        // Pass 1: chunk-local affine composition (Ac, Wc)
        float Ac = 1.f, Wc = 0.f;
        for (int i = 0; i < 32; i++) {
            const int ll = lbase + i;
            const float dl = sdl[ll * 33 + d];
            const float ul = su[d * 132 + ll];
            const float w  = (dl * ul) * sB[ll * 9 + n];
            const float dA = __expf(dl * A);
            Wc = dA * Wc + w;
            Ac *= dA;
        }
        // Exclusive prefix over the 4 chunks (lanes 4m..4m+3 share (d,n))
        float h0 = 0.f;
#pragma unroll
        for (int j = 0; j < 3; j++) {
            const float Aj = __shfl(Ac, j, 4);
            const float Wj = __shfl(Wc, j, 4);
            if (j < c) h0 = Aj * h0 + Wj;
        }
        // Pass 2: rescan chunk from h0, emitting y to LDS
        float hst = h0;
        for (int i = 0; i < 32; i++) {
            const int ll = lbase + i;
            const float dl = sdl[ll * 33 + d];
            const float ul = su[d * 132 + ll];
            const float Bv = sB[ll * 9 + n];
            const float Cv = sC[ll * 9 + n];
            const float dA = __expf(dl * A);
            hst = dA * hst + (dl * ul) * Bv;
            float y = hst * Cv;
            y += __shfl_xor(y, 4);
            y += __shfl_xor(y, 8);
            y += __shfl_xor(y, 16);
            if (n == 0) sy[d * 132 + ll] = y + Dd * ul;
        }
    }
    __syncthreads();

    // Phase 7: store y (fwd orientation, [b][d][l]) to global; coalesced
    for (int i = tid; i < 4096; i += 1024) {
        const int d = i >> 7, li = i & 127;
        const int gl = dir ? (127 - li) : li;
        g_y[dir][(b * D_M + d) * L_SEQ + gl] = sy[d * 132 + li];
    }
    __syncthreads();

    // Arrival: last block of this batch runs the final stage
    if (tid == 0) {
        __threadfence();
        const int old = atomicAdd(&g_done[b], 1);
        const int win = (old == 1);
        if (win) {
            atomicExch(&g_done[b], 0);
            __threadfence();
        }
        s_flag = win;
    }
    __syncthreads();
    if (!s_flag) return;

    // ---- Parallel final (all 1024 threads of winner) ----
    {
        float* sv = S;            // [128][33]
        float* sp = S + 4352;     // [8][128]
        const float* y0 = g_y[0] + (size_t)b * D_M * L_SEQ;
        const float* y1 = g_y[1] + (size_t)b * D_M * L_SEQ;

        // v[d] = (y0+y1)[d][l] * silu(z[d]) for this thread's 4 d's
#pragma unroll
        for (int k = 0; k < 4; k++) {
            const int d = qq * 4 + k;
            const float yc = y0[d * L_SEQ + l] + y1[d * L_SEQ + l];
            sv[l * 33 + d] = yc * zs[k];
        }
        __syncthreads();

        // LN stats (redundant x8 per l) + 4 out_proj rows + w2 partial
        float vv[D_M];
        float mean = 0.f;
#pragma unroll
        for (int d = 0; d < D_M; d++) { vv[d] = sv[l * 33 + d]; mean += vv[d]; }
        mean *= (1.f / D_M);
        float var = 0.f;
#pragma unroll
        for (int d = 0; d < D_M; d++) { float t = vv[d] - mean; var += t * t; }
        var *= (1.f / D_M);
        const float rs = rsqrtf(var + 1e-5f);
#pragma unroll
        for (int d = 0; d < D_M; d++)
            vv[d] = ((vv[d] - mean) * rs * ng[d] + nb[d]) * 0.5f;

        float accp = 0.f;
#pragma unroll
        for (int k = 0; k < 4; k++) {
            const int o = qq * 4 + k;
            float t = 0.f;
#pragma unroll
            for (int d = 0; d < D_M; d++) t += vv[d] * Wout[o * 32 + d];
            accp += t * w2[o];
        }
        sp[qq * 128 + l] = accp;
        __syncthreads();

        if (tid < 128) {
            float acc = b2[0];
#pragma unroll
            for (int j = 0; j < 8; j++) acc += sp[j * 128 + tid];
            out[b * L_SEQ + tid] = 1.f / (1.f + __expf(-acc));
        }
    }
}

extern "C" void kernel_launch(void* const* d_in, const int* in_sizes, int n_in,
                              void* d_out, int out_size, void* d_ws, size_t ws_size,
                              hipStream_t stream) {
    const float* x        = (const float*)d_in[0];
    const float* w1       = (const float*)d_in[1];
    const float* b1       = (const float*)d_in[2];
    const float* ln_g     = (const float*)d_in[3];
    const float* ln_b     = (const float*)d_in[4];
    const float* in_proj  = (const float*)d_in[5];
    const float* cw_f     = (const float*)d_in[6];
    const float* cb_f     = (const float*)d_in[7];
    const float* xp_f     = (const float*)d_in[8];
    const float* dtw_f    = (const float*)d_in[9];
    const float* dtb_f    = (const float*)d_in[10];
    const float* Al_f     = (const float*)d_in[11];
    const float* Dp_f     = (const float*)d_in[12];
    const float* cw_b     = (const float*)d_in[13];
    const float* cb_b     = (const float*)d_in[14];
    const float* xp_b     = (const float*)d_in[15];
    const float* dtw_b    = (const float*)d_in[16];
    const float* dtb_b    = (const float*)d_in[17];
    const float* Al_b     = (const float*)d_in[18];
    const float* Dp_b     = (const float*)d_in[19];
    const float* norm_g   = (const float*)d_in[20];
    const float* norm_b   = (const float*)d_in[21];
    const float* Wout     = (const float*)d_in[22];
    const float* w2       = (const float*)d_in[23];
    const float* b2       = (const float*)d_in[24];

    kmax<<<NROWS * NCHUNK, 256, 0, stream>>>(x);
    ktail<<<B_SZ * 2, 1024, 0, stream>>>(w1, b1, ln_g, ln_b, in_proj,
                                         cw_f, cb_f, xp_f, dtw_f, dtb_f, Al_f, Dp_f,
                                         cw_b, cb_b, xp_b, dtw_b, dtb_b, Al_b, Dp_b,
                                         norm_g, norm_b, Wout, w2, b2, (float*)d_out);
}

// Round 13
// 110.866 us; speedup vs baseline: 1.4583x; 1.0190x over previous
//
#include <hip/hip_runtime.h>
#include <hip/hip_bf16.h>
#include <math.h>

#define B_SZ 16
#define L_SEQ 128
#define D_M 32
#define HW 65536           // 256*256
#define NROWS (B_SZ * 128) // 2048 (b,c) rows
#define NCHUNK 2           // chunks per row for kmax

typedef float vfloat4 __attribute__((ext_vector_type(4)));

// Device-global scratch
__device__ float g_part[NROWS * NCHUNK];          // partial maxima
__device__ float g_y[2][B_SZ * D_M * L_SEQ];      // per-dir y, [b][d][l], fwd orientation
__device__ int   g_done[B_SZ];                    // arrival counters (self-resetting)

__device__ __forceinline__ float silu_acc(float x) {
    return x / (1.f + __expf(-x));
}
__device__ __forceinline__ float softplusf(float x) {
    return (x > 20.f) ? x : log1pf(__expf(x));
}

__device__ __forceinline__ float row_max(int row) {
    const int r2 = row * NCHUNK;
    return fmaxf(g_part[r2], g_part[r2 + 1]);
}

// h[0..31] = LN(s*w1+b1), in registers; weights via uniform scalar loads.
__device__ __forceinline__ void compute_h(int row, const float* __restrict__ w1,
                                          const float* __restrict__ b1,
                                          const float* __restrict__ lng,
                                          const float* __restrict__ lnb,
                                          float h[D_M]) {
    const float s = row_max(row);
    float mean = 0.f;
#pragma unroll
    for (int d = 0; d < D_M; d++) { h[d] = s * w1[d] + b1[d]; mean += h[d]; }
    mean *= (1.f / D_M);
    float var = 0.f;
#pragma unroll
    for (int d = 0; d < D_M; d++) { float t = h[d] - mean; var += t * t; }
    var *= (1.f / D_M);
    const float rs = rsqrtf(var + 1e-5f);
#pragma unroll
    for (int d = 0; d < D_M; d++) h[d] = (h[d] - mean) * rs * lng[d] + lnb[d];
}

// ---------------- K1: partial max over half-rows (R7 verbatim, NT loads) ----------------
__global__ __launch_bounds__(256) void kmax(const float* __restrict__ x) {
    const int blk = blockIdx.x;                 // 0..4095
    const vfloat4* __restrict__ p =
        reinterpret_cast<const vfloat4*>(x) + (size_t)blk * 8192;
    const int t = threadIdx.x;
    float m0 = -INFINITY, m1 = -INFINITY, m2 = -INFINITY, m3 = -INFINITY;
#pragma unroll
    for (int i = 0; i < 8192; i += 1024) {
        vfloat4 v0 = __builtin_nontemporal_load(p + i + t);
        vfloat4 v1 = __builtin_nontemporal_load(p + i + t + 256);
        vfloat4 v2 = __builtin_nontemporal_load(p + i + t + 512);
        vfloat4 v3 = __builtin_nontemporal_load(p + i + t + 768);
        m0 = fmaxf(m0, fmaxf(fmaxf(v0.x, v0.y), fmaxf(v0.z, v0.w)));
        m1 = fmaxf(m1, fmaxf(fmaxf(v1.x, v1.y), fmaxf(v1.z, v1.w)));
        m2 = fmaxf(m2, fmaxf(fmaxf(v2.x, v2.y), fmaxf(v2.z, v2.w)));
        m3 = fmaxf(m3, fmaxf(fmaxf(v3.x, v3.y), fmaxf(v3.z, v3.w)));
    }
    float m = fmaxf(fmaxf(m0, m1), fmaxf(m2, m3));
#pragma unroll
    for (int off = 32; off >= 1; off >>= 1)
        m = fmaxf(m, __shfl_xor(m, off));
    __shared__ float sm[4];
    if ((threadIdx.x & 63) == 0) sm[threadIdx.x >> 6] = m;
    __syncthreads();
    if (threadIdx.x == 0)
        g_part[blk] = fmaxf(fmaxf(sm[0], sm[1]), fmaxf(sm[2], sm[3]));
}

// ---------------- K2: per (batch, direction), 1024 threads (R12 base + m-folded final) ----------------
// LDS word map (15392 = 61.6 KB):
//  [0,4352)      sx  [32][136] pad4 / sdl overlay [128][33] / sv overlay [128][33] (final)
//  [4352,8576)   su  [32][132]
//  [8576,12800)  sy  [32][132]
//  [12800,13056) sdt [128][2]
//  [13056,14208) sB  [128][9]
//  [14208,15360) sC  [128][9]
//  [15360,15392) smm [32]  (m = Wout^T @ w2, weight-only)
__global__ __launch_bounds__(1024) void ktail(
    const float* __restrict__ w1,  const float* __restrict__ b1,
    const float* __restrict__ lng, const float* __restrict__ lnb,
    const float* __restrict__ Win,
    const float* __restrict__ cw_f, const float* __restrict__ cb_f,
    const float* __restrict__ xp_f, const float* __restrict__ dtw_f,
    const float* __restrict__ dtb_f, const float* __restrict__ Al_f,
    const float* __restrict__ Dp_f,
    const float* __restrict__ cw_b, const float* __restrict__ cb_b,
    const float* __restrict__ xp_b, const float* __restrict__ dtw_b,
    const float* __restrict__ dtb_b, const float* __restrict__ Al_b,
    const float* __restrict__ Dp_b,
    const float* __restrict__ ng,  const float* __restrict__ nb,
    const float* __restrict__ Wout, const float* __restrict__ w2,
    const float* __restrict__ b2,  float* __restrict__ out) {
    const int b   = blockIdx.x >> 1;
    const int dir = blockIdx.x & 1;
    const int tid = threadIdx.x;

    const float* cw  = dir ? cw_b  : cw_f;
    const float* cb  = dir ? cb_b  : cb_f;
    const float* xp  = dir ? xp_b  : xp_f;
    const float* dtw = dir ? dtw_b : dtw_f;
    const float* dtb = dir ? dtb_b : dtb_f;
    const float* Al  = dir ? Al_b  : Al_f;
    const float* Dp  = dir ? Dp_b  : Dp_f;

    __shared__ __align__(16) float S[15392];
    __shared__ int s_flag;
    float* sx  = S;            // [32][136], data at +4
    float* sdl = S;            // [128][33] overlay (after conv consumed sx)
    float* su  = S + 4352;     // [32][132]
    float* sy  = S + 8576;     // [32][132]
    float* sdt = S + 12800;    // [128][2]
    float* sB  = S + 13056;    // [128][9]
    float* sC  = S + 14208;    // [128][9]
    float* smm = S + 15360;    // [32]

    const int l = tid & 127;
    const int q = tid >> 7;    // 0..7 (wave-uniform)
    const int qq = __builtin_amdgcn_readfirstlane(q);

    // Phase 1: zero conv front-pad; m = Wout^T @ w2; h in registers
    if (tid < 128) sx[(tid >> 2) * 136 + (tid & 3)] = 0.f;
    if (tid >= 128 && tid < 160) {
        const int d = tid - 128;
        float mm = 0.f;
#pragma unroll
        for (int o = 0; o < D_M; o++) mm += w2[o] * Wout[o * 32 + d];
        smm[d] = mm;
    }
    float h[D_M];
    compute_h(b * L_SEQ + l, w1, b1, lng, lnb, h);

    // Phase 2: x-half GEMV (scalar-load weights), stored pre-flipped; 4 rows/thread
    {
        const int lw = dir ? (127 - l) : l;
#pragma unroll
        for (int k = 0; k < 4; k++) {
            const int e = qq * 4 + k;
            float acc = 0.f;
#pragma unroll
            for (int d = 0; d < D_M; d++) acc += h[d] * Win[e * 32 + d];
            sx[e * 136 + 4 + lw] = acc;
        }
    }

    // z pre-compute (pre-arrival; depends only on h): zs[k] = silu(z[qq*4+k])
    float zs[4];
#pragma unroll
    for (int k = 0; k < 4; k++) {
        const int d = qq * 4 + k;
        float z = 0.f;
#pragma unroll
        for (int kk = 0; kk < D_M; kk++) z += h[kk] * Win[(32 + d) * 32 + kk];
        zs[k] = silu_acc(z);
    }
    __syncthreads();

    // Phase 3: causal conv(4) + SiLU; thread = (d, 4-l block)
    {
        const int d  = tid >> 5;          // 0..31
        const int l0 = (tid & 31) * 4;    // 0,4,...,124
        const vfloat4* px = reinterpret_cast<const vfloat4*>(sx + d * 136 + l0);
        vfloat4 a0 = px[0], a1 = px[1];   // data l0-4..l0-1, l0..l0+3
        float xv[7] = {a0.y, a0.z, a0.w, a1.x, a1.y, a1.z, a1.w};
        const float c0 = cw[d*4+0], c1 = cw[d*4+1], c2 = cw[d*4+2], c3 = cw[d*4+3];
        const float cbd = cb[d];
        float uo[4];
#pragma unroll
        for (int j = 0; j < 4; j++) {
            float acc = cbd + c0*xv[j] + c1*xv[j+1] + c2*xv[j+2] + c3*xv[j+3];
            uo[j] = silu_acc(acc);
        }
        vfloat4 u0 = {uo[0], uo[1], uo[2], uo[3]};
        *reinterpret_cast<vfloat4*>(su + d * 132 + l0) = u0;
    }
    __syncthreads();

    // Phase 4: x_dbl = u^T @ xp^T; rows r = qq, qq+8, (qq<2: qq+16)
    {
        float ul[D_M];
#pragma unroll
        for (int d = 0; d < D_M; d++) ul[d] = su[d * 132 + l];
#pragma unroll
        for (int rep = 0; rep < 3; rep++) {
            const int r = qq + rep * 8;
            if (rep == 2 && qq >= 2) break;
            float acc = 0.f;
#pragma unroll
            for (int d = 0; d < D_M; d++) acc += ul[d] * xp[r * 32 + d];
            if (r < 2)       sdt[l * 2 + r] = acc;
            else if (r < 10) sB[l * 9 + (r - 2)] = acc;
            else             sC[l * 9 + (r - 10)] = acc;
        }
    }
    __syncthreads();

    // Phase 5: delta = softplus(dt @ dtw^T + dtb), overlays sx; 4 d's/thread
    {
        const float dt0 = sdt[l * 2 + 0], dt1 = sdt[l * 2 + 1];
        const int d0 = qq * 4;
#pragma unroll
        for (int j = 0; j < 4; j++) {
            const int d = d0 + j;
            const float t = dt0 * dtw[d * 2 + 0] + dt1 * dtw[d * 2 + 1] + dtb[d];
            sdl[l * 33 + d] = softplusf(t);
        }
    }
    __syncthreads();

    // Phase 6: chunked parallel scan. thread = (d, n, c): 32*8*4 = 1024.
    {
        const int d = tid >> 5;
        const int n = (tid >> 2) & 7;
        const int c = tid & 3;
        const float A  = -__expf(Al[d * 8 + n]);
        const float Dd = Dp[d];
        const int lbase = c * 32;

        // Pass 1: chunk-local affine composition (Ac, Wc)
        float Ac = 1.f, Wc = 0.f;
        for (int i = 0; i < 32; i++) {
            const int ll = lbase + i;
            const float dl = sdl[ll * 33 + d];
            const float ul = su[d * 132 + ll];
            const float w  = (dl * ul) * sB[ll * 9 + n];
            const float dA = __expf(dl * A);
            Wc = dA * Wc + w;
            Ac *= dA;
        }
        // Exclusive prefix over the 4 chunks (lanes 4m..4m+3 share (d,n))
        float h0 = 0.f;
#pragma unroll
        for (int j = 0; j < 3; j++) {
            const float Aj = __shfl(Ac, j, 4);
            const float Wj = __shfl(Wc, j, 4);
            if (j < c) h0 = Aj * h0 + Wj;
        }
        // Pass 2: rescan chunk from h0, emitting y to LDS
        float hst = h0;
        for (int i = 0; i < 32; i++) {
            const int ll = lbase + i;
            const float dl = sdl[ll * 33 + d];
            const float ul = su[d * 132 + ll];
            const float Bv = sB[ll * 9 + n];
            const float Cv = sC[ll * 9 + n];
            const float dA = __expf(dl * A);
            hst = dA * hst + (dl * ul) * Bv;
            float y = hst * Cv;
            y += __shfl_xor(y, 4);
            y += __shfl_xor(y, 8);
            y += __shfl_xor(y, 16);
            if (n == 0) sy[d * 132 + ll] = y + Dd * ul;
        }
    }
    __syncthreads();

    // Phase 7: store y (fwd orientation, [b][d][l]) to global; coalesced
    for (int i = tid; i < 4096; i += 1024) {
        const int d = i >> 7, li = i & 127;
        const int gl = dir ? (127 - li) : li;
        g_y[dir][(b * D_M + d) * L_SEQ + gl] = sy[d * 132 + li];
    }
    __syncthreads();

    // Arrival: last block of this batch runs the final stage
    if (tid == 0) {
        __threadfence();
        const int old = atomicAdd(&g_done[b], 1);
        const int win = (old == 1);
        if (win) {
            atomicExch(&g_done[b], 0);
            __threadfence();
        }
        s_flag = win;
    }
    __syncthreads();
    if (!s_flag) return;

    // ---- Final (winner): v build by all threads, then 128 threads LN + m-dot ----
    {
        float* sv = S;            // [128][33]
        const float* y0 = g_y[0] + (size_t)b * D_M * L_SEQ;
        const float* y1 = g_y[1] + (size_t)b * D_M * L_SEQ;

        // v[d] = (y0+y1)[d][l] * silu(z[d]) for this thread's 4 d's
#pragma unroll
        for (int k = 0; k < 4; k++) {
            const int d = qq * 4 + k;
            const float yc = y0[d * L_SEQ + l] + y1[d * L_SEQ + l];
            sv[l * 33 + d] = yc * zs[k];
        }
        __syncthreads();

        if (tid < 128) {
            float vv[D_M];
            float mean = 0.f;
#pragma unroll
            for (int d = 0; d < D_M; d++) { vv[d] = sv[l * 33 + d]; mean += vv[d]; }
            mean *= (1.f / D_M);
            float var = 0.f;
#pragma unroll
            for (int d = 0; d < D_M; d++) { float t = vv[d] - mean; var += t * t; }
            var *= (1.f / D_M);
            const float rs = rsqrtf(var + 1e-5f);

            float acc = b2[0];
#pragma unroll
            for (int d = 0; d < D_M; d++) {
                const float y = ((vv[d] - mean) * rs * ng[d] + nb[d]) * 0.5f;
                acc += y * smm[d];
            }
            out[b * L_SEQ + l] = 1.f / (1.f + __expf(-acc));
        }
    }
}

extern "C" void kernel_launch(void* const* d_in, const int* in_sizes, int n_in,
                              void* d_out, int out_size, void* d_ws, size_t ws_size,
                              hipStream_t stream) {
    const float* x        = (const float*)d_in[0];
    const float* w1       = (const float*)d_in[1];
    const float* b1       = (const float*)d_in[2];
    const float* ln_g     = (const float*)d_in[3];
    const float* ln_b     = (const float*)d_in[4];
    const float* in_proj  = (const float*)d_in[5];
    const float* cw_f     = (const float*)d_in[6];
    const float* cb_f     = (const float*)d_in[7];
    const float* xp_f     = (const float*)d_in[8];
    const float* dtw_f    = (const float*)d_in[9];
    const float* dtb_f    = (const float*)d_in[10];
    const float* Al_f     = (const float*)d_in[11];
    const float* Dp_f     = (const float*)d_in[12];
    const float* cw_b     = (const float*)d_in[13];
    const float* cb_b     = (const float*)d_in[14];
    const float* xp_b     = (const float*)d_in[15];
    const float* dtw_b    = (const float*)d_in[16];
    const float* dtb_b    = (const float*)d_in[17];
    const float* Al_b     = (const float*)d_in[18];
    const float* Dp_b     = (const float*)d_in[19];
    const float* norm_g   = (const float*)d_in[20];
    const float* norm_b   = (const float*)d_in[21];
    const float* Wout     = (const float*)d_in[22];
    const float* w2       = (const float*)d_in[23];
    const float* b2       = (const float*)d_in[24];

    kmax<<<NROWS * NCHUNK, 256, 0, stream>>>(x);
    ktail<<<B_SZ * 2, 1024, 0, stream>>>(w1, b1, ln_g, ln_b, in_proj,
                                         cw_f, cb_f, xp_f, dtw_f, dtb_f, Al_f, Dp_f,
                                         cw_b, cb_b, xp_b, dtw_b, dtb_b, Al_b, Dp_b,
                                         norm_g, norm_b, Wout, w2, b2, (float*)d_out);
}

// Round 14
// 102.382 us; speedup vs baseline: 1.5792x; 1.0829x over previous
//
#include <hip/hip_runtime.h>
#include <hip/hip_bf16.h>
#include <math.h>

#define B_SZ 16
#define L_SEQ 128
#define D_M 32
#define HW 65536           // 256*256
#define NROWS (B_SZ * 128) // 2048 (b,c) rows
#define NCHUNK 2           // chunks per row for kmax

typedef float vfloat4 __attribute__((ext_vector_type(4)));

// Device-global scratch
__device__ float g_part[NROWS * NCHUNK];          // partial maxima
__device__ float g_y[2][B_SZ * D_M * L_SEQ];      // per-dir y, [b][d][l], fwd orientation
__device__ int   g_done[B_SZ];                    // arrival counters (self-resetting)

__device__ __forceinline__ float silu_acc(float x) {
    return x / (1.f + __expf(-x));
}
__device__ __forceinline__ float softplusf(float x) {
    return (x > 20.f) ? x : log1pf(__expf(x));
}

__device__ __forceinline__ float row_max(int row) {
    const int r2 = row * NCHUNK;
    return fmaxf(g_part[r2], g_part[r2 + 1]);
}

// h[0..31] = LN(s*w1+b1), in registers; weights via uniform scalar loads.
__device__ __forceinline__ void compute_h(int row, const float* __restrict__ w1,
                                          const float* __restrict__ b1,
                                          const float* __restrict__ lng,
                                          const float* __restrict__ lnb,
                                          float h[D_M]) {
    const float s = row_max(row);
    float mean = 0.f;
#pragma unroll
    for (int d = 0; d < D_M; d++) { h[d] = s * w1[d] + b1[d]; mean += h[d]; }
    mean *= (1.f / D_M);
    float var = 0.f;
#pragma unroll
    for (int d = 0; d < D_M; d++) { float t = h[d] - mean; var += t * t; }
    var *= (1.f / D_M);
    const float rs = rsqrtf(var + 1e-5f);
#pragma unroll
    for (int d = 0; d < D_M; d++) h[d] = (h[d] - mean) * rs * lng[d] + lnb[d];
}

// ---------------- K1: partial max over half-rows (R7 verbatim, NT loads) ----------------
__global__ __launch_bounds__(256) void kmax(const float* __restrict__ x) {
    const int blk = blockIdx.x;                 // 0..4095
    const vfloat4* __restrict__ p =
        reinterpret_cast<const vfloat4*>(x) + (size_t)blk * 8192;
    const int t = threadIdx.x;
    float m0 = -INFINITY, m1 = -INFINITY, m2 = -INFINITY, m3 = -INFINITY;
#pragma unroll
    for (int i = 0; i < 8192; i += 1024) {
        vfloat4 v0 = __builtin_nontemporal_load(p + i + t);
        vfloat4 v1 = __builtin_nontemporal_load(p + i + t + 256);
        vfloat4 v2 = __builtin_nontemporal_load(p + i + t + 512);
        vfloat4 v3 = __builtin_nontemporal_load(p + i + t + 768);
        m0 = fmaxf(m0, fmaxf(fmaxf(v0.x, v0.y), fmaxf(v0.z, v0.w)));
        m1 = fmaxf(m1, fmaxf(fmaxf(v1.x, v1.y), fmaxf(v1.z, v1.w)));
        m2 = fmaxf(m2, fmaxf(fmaxf(v2.x, v2.y), fmaxf(v2.z, v2.w)));
        m3 = fmaxf(m3, fmaxf(fmaxf(v3.x, v3.y), fmaxf(v3.z, v3.w)));
    }
    float m = fmaxf(fmaxf(m0, m1), fmaxf(m2, m3));
#pragma unroll
    for (int off = 32; off >= 1; off >>= 1)
        m = fmaxf(m, __shfl_xor(m, off));
    __shared__ float sm[4];
    if ((threadIdx.x & 63) == 0) sm[threadIdx.x >> 6] = m;
    __syncthreads();
    if (threadIdx.x == 0)
        g_part[blk] = fmaxf(fmaxf(sm[0], sm[1]), fmaxf(sm[2], sm[3]));
}

// ---------------- K2: per (batch, direction), 1024 threads (R13 base + scan redesign) ----------------
// LDS word map (15136 words = 60.5 KB):
//  [0,4352)      sx  [32][136] pad4 / sdl overlay [128][33] / sv overlay [128][33] (final)
//  [4352,8576)   su  [32][132]
//  [8576,12800)  sy  [32][132]
//  [12800,13056) sdt [128][2]
//  [13056,14080) sB  [128][8]  (stride 8: b128-vectorizable, broadcast reads)
//  [14080,15104) sC  [128][8]
//  [15104,15136) smm [32]  (m = Wout^T @ w2, weight-only)
__global__ __launch_bounds__(1024) void ktail(
    const float* __restrict__ w1,  const float* __restrict__ b1,
    const float* __restrict__ lng, const float* __restrict__ lnb,
    const float* __restrict__ Win,
    const float* __restrict__ cw_f, const float* __restrict__ cb_f,
    const float* __restrict__ xp_f, const float* __restrict__ dtw_f,
    const float* __restrict__ dtb_f, const float* __restrict__ Al_f,
    const float* __restrict__ Dp_f,
    const float* __restrict__ cw_b, const float* __restrict__ cb_b,
    const float* __restrict__ xp_b, const float* __restrict__ dtw_b,
    const float* __restrict__ dtb_b, const float* __restrict__ Al_b,
    const float* __restrict__ Dp_b,
    const float* __restrict__ ng,  const float* __restrict__ nb,
    const float* __restrict__ Wout, const float* __restrict__ w2,
    const float* __restrict__ b2,  float* __restrict__ out) {
    const int b   = blockIdx.x >> 1;
    const int dir = blockIdx.x & 1;
    const int tid = threadIdx.x;

    const float* cw  = dir ? cw_b  : cw_f;
    const float* cb  = dir ? cb_b  : cb_f;
    const float* xp  = dir ? xp_b  : xp_f;
    const float* dtw = dir ? dtw_b : dtw_f;
    const float* dtb = dir ? dtb_b : dtb_f;
    const float* Al  = dir ? Al_b  : Al_f;
    const float* Dp  = dir ? Dp_b  : Dp_f;

    __shared__ __align__(16) float S[15136];
    __shared__ int s_flag;
    float* sx  = S;            // [32][136], data at +4
    float* sdl = S;            // [128][33] overlay (after conv consumed sx)
    float* su  = S + 4352;     // [32][132]
    float* sy  = S + 8576;     // [32][132]
    float* sdt = S + 12800;    // [128][2]
    float* sB  = S + 13056;    // [128][8]
    float* sC  = S + 14080;    // [128][8]
    float* smm = S + 15104;    // [32]

    const int l = tid & 127;
    const int q = tid >> 7;    // 0..7 (wave-uniform)
    const int qq = __builtin_amdgcn_readfirstlane(q);

    // Phase 1: zero conv front-pad; m = Wout^T @ w2; h in registers
    if (tid < 128) sx[(tid >> 2) * 136 + (tid & 3)] = 0.f;
    if (tid >= 128 && tid < 160) {
        const int d = tid - 128;
        float mm = 0.f;
#pragma unroll
        for (int o = 0; o < D_M; o++) mm += w2[o] * Wout[o * 32 + d];
        smm[d] = mm;
    }
    float h[D_M];
    compute_h(b * L_SEQ + l, w1, b1, lng, lnb, h);

    // Phase 2: x-half GEMV (scalar-load weights), stored pre-flipped; 4 rows/thread
    {
        const int lw = dir ? (127 - l) : l;
#pragma unroll
        for (int k = 0; k < 4; k++) {
            const int e = qq * 4 + k;
            float acc = 0.f;
#pragma unroll
            for (int d = 0; d < D_M; d++) acc += h[d] * Win[e * 32 + d];
            sx[e * 136 + 4 + lw] = acc;
        }
    }

    // z pre-compute (pre-arrival; depends only on h): zs[k] = silu(z[qq*4+k])
    float zs[4];
#pragma unroll
    for (int k = 0; k < 4; k++) {
        const int d = qq * 4 + k;
        float z = 0.f;
#pragma unroll
        for (int kk = 0; kk < D_M; kk++) z += h[kk] * Win[(32 + d) * 32 + kk];
        zs[k] = silu_acc(z);
    }
    __syncthreads();

    // Phase 3: causal conv(4) + SiLU; thread = (d, 4-l block)
    {
        const int d  = tid >> 5;          // 0..31
        const int l0 = (tid & 31) * 4;    // 0,4,...,124
        const vfloat4* px = reinterpret_cast<const vfloat4*>(sx + d * 136 + l0);
        vfloat4 a0 = px[0], a1 = px[1];   // data l0-4..l0-1, l0..l0+3
        float xv[7] = {a0.y, a0.z, a0.w, a1.x, a1.y, a1.z, a1.w};
        const float c0 = cw[d*4+0], c1 = cw[d*4+1], c2 = cw[d*4+2], c3 = cw[d*4+3];
        const float cbd = cb[d];
        float uo[4];
#pragma unroll
        for (int j = 0; j < 4; j++) {
            float acc = cbd + c0*xv[j] + c1*xv[j+1] + c2*xv[j+2] + c3*xv[j+3];
            uo[j] = silu_acc(acc);
        }
        vfloat4 u0 = {uo[0], uo[1], uo[2], uo[3]};
        *reinterpret_cast<vfloat4*>(su + d * 132 + l0) = u0;
    }
    __syncthreads();

    // Phase 4: x_dbl = u^T @ xp^T; rows r = qq, qq+8, (qq<2: qq+16)
    {
        float ul[D_M];
#pragma unroll
        for (int d = 0; d < D_M; d++) ul[d] = su[d * 132 + l];
#pragma unroll
        for (int rep = 0; rep < 3; rep++) {
            const int r = qq + rep * 8;
            if (rep == 2 && qq >= 2) break;
            float acc = 0.f;
#pragma unroll
            for (int d = 0; d < D_M; d++) acc += ul[d] * xp[r * 32 + d];
            if (r < 2)       sdt[l * 2 + r] = acc;
            else if (r < 10) sB[l * 8 + (r - 2)] = acc;
            else             sC[l * 8 + (r - 10)] = acc;
        }
    }
    __syncthreads();

    // Phase 5: delta = softplus(dt @ dtw^T + dtb), overlays sx; 4 d's/thread
    {
        const float dt0 = sdt[l * 2 + 0], dt1 = sdt[l * 2 + 1];
        const int d0 = qq * 4;
#pragma unroll
        for (int j = 0; j < 4; j++) {
            const int d = d0 + j;
            const float t = dt0 * dtw[d * 2 + 0] + dt1 * dtw[d * 2 + 1] + dtb[d];
            sdl[l * 33 + d] = softplusf(t);
        }
    }
    __syncthreads();

    // Phase 6: chunked scan, thread = (d, c): 32*8 = 256 threads, 8 n-states in regs
    if (tid < 256) {
        const int d = tid >> 3;       // 0..31
        const int c = tid & 7;        // 0..7 (== lane&7, since 8 | 64)
        float An[8];
        {
            const vfloat4* ap = reinterpret_cast<const vfloat4*>(Al + d * 8);
            vfloat4 a0 = ap[0], a1 = ap[1];
            An[0]=a0.x; An[1]=a0.y; An[2]=a0.z; An[3]=a0.w;
            An[4]=a1.x; An[5]=a1.y; An[6]=a1.z; An[7]=a1.w;
#pragma unroll
            for (int n = 0; n < 8; n++) An[n] = -__expf(An[n]);
        }
        const float Dd = Dp[d];
        const int lbase = c * 16;

        // Pass 1: chunk-local affine composition per n: (Ap, Wp)
        float Ap[8], Wp[8];
#pragma unroll
        for (int n = 0; n < 8; n++) { Ap[n] = 1.f; Wp[n] = 0.f; }
        for (int i = 0; i < 16; i++) {
            const int ll = lbase + i;
            const float dl = sdl[ll * 33 + d];
            const float ul = su[d * 132 + ll];
            const float du = dl * ul;
            const vfloat4* bp = reinterpret_cast<const vfloat4*>(sB + ll * 8);
            vfloat4 b0 = bp[0], b1 = bp[1];
            float Bv[8] = {b0.x,b0.y,b0.z,b0.w,b1.x,b1.y,b1.z,b1.w};
#pragma unroll
            for (int n = 0; n < 8; n++) {
                const float dA = __expf(dl * An[n]);
                Wp[n] = dA * Wp[n] + du * Bv[n];
                Ap[n] *= dA;
            }
        }
        // Inclusive affine scan over the 8 c-lanes (Hillis-Steele), per n
#pragma unroll
        for (int s = 1; s < 8; s <<= 1) {
#pragma unroll
            for (int n = 0; n < 8; n++) {
                const float Au = __shfl_up(Ap[n], s, 8);
                const float Wu = __shfl_up(Wp[n], s, 8);
                if (c >= s) {
                    Wp[n] = Ap[n] * Wu + Wp[n];
                    Ap[n] = Ap[n] * Au;
                }
            }
        }
        // Exclusive: h0 = state after chunks [0..c-1]
        float hn[8];
#pragma unroll
        for (int n = 0; n < 8; n++) {
            const float Wu = __shfl_up(Wp[n], 1, 8);
            hn[n] = (c == 0) ? 0.f : Wu;
        }
        // Pass 2: rescan from h0, emitting y
        for (int i = 0; i < 16; i++) {
            const int ll = lbase + i;
            const float dl = sdl[ll * 33 + d];
            const float ul = su[d * 132 + ll];
            const float du = dl * ul;
            const vfloat4* bp = reinterpret_cast<const vfloat4*>(sB + ll * 8);
            const vfloat4* cp = reinterpret_cast<const vfloat4*>(sC + ll * 8);
            vfloat4 b0 = bp[0], b1 = bp[1];
            vfloat4 c0 = cp[0], c1 = cp[1];
            float Bv[8] = {b0.x,b0.y,b0.z,b0.w,b1.x,b1.y,b1.z,b1.w};
            float Cv[8] = {c0.x,c0.y,c0.z,c0.w,c1.x,c1.y,c1.z,c1.w};
            float y = 0.f;
#pragma unroll
            for (int n = 0; n < 8; n++) {
                const float dA = __expf(dl * An[n]);
                hn[n] = dA * hn[n] + du * Bv[n];
                y += hn[n] * Cv[n];
            }
            sy[d * 132 + ll] = y + Dd * ul;
        }
    }
    __syncthreads();

    // Phase 7: store y (fwd orientation, [b][d][l]) to global; coalesced
    for (int i = tid; i < 4096; i += 1024) {
        const int d = i >> 7, li = i & 127;
        const int gl = dir ? (127 - li) : li;
        g_y[dir][(b * D_M + d) * L_SEQ + gl] = sy[d * 132 + li];
    }
    __syncthreads();

    // Arrival: last block of this batch runs the final stage
    if (tid == 0) {
        __threadfence();
        const int old = atomicAdd(&g_done[b], 1);
        const int win = (old == 1);
        if (win) {
            atomicExch(&g_done[b], 0);
            __threadfence();
        }
        s_flag = win;
    }
    __syncthreads();
    if (!s_flag) return;

    // ---- Final (winner): v build by all threads, then 128 threads LN + m-dot ----
    {
        float* sv = S;            // [128][33]
        const float* y0 = g_y[0] + (size_t)b * D_M * L_SEQ;
        const float* y1 = g_y[1] + (size_t)b * D_M * L_SEQ;

#pragma unroll
        for (int k = 0; k < 4; k++) {
            const int d = qq * 4 + k;
            const float yc = y0[d * L_SEQ + l] + y1[d * L_SEQ + l];
            sv[l * 33 + d] = yc * zs[k];
        }
        __syncthreads();

        if (tid < 128) {
            float vv[D_M];
            float mean = 0.f;
#pragma unroll
            for (int d = 0; d < D_M; d++) { vv[d] = sv[l * 33 + d]; mean += vv[d]; }
            mean *= (1.f / D_M);
            float var = 0.f;
#pragma unroll
            for (int d = 0; d < D_M; d++) { float t = vv[d] - mean; var += t * t; }
            var *= (1.f / D_M);
            const float rs = rsqrtf(var + 1e-5f);

            float acc = b2[0];
#pragma unroll
            for (int d = 0; d < D_M; d++) {
                const float y = ((vv[d] - mean) * rs * ng[d] + nb[d]) * 0.5f;
                acc += y * smm[d];
            }
            out[b * L_SEQ + l] = 1.f / (1.f + __expf(-acc));
        }
    }
}

extern "C" void kernel_launch(void* const* d_in, const int* in_sizes, int n_in,
                              void* d_out, int out_size, void* d_ws, size_t ws_size,
                              hipStream_t stream) {
    const float* x        = (const float*)d_in[0];
    const float* w1       = (const float*)d_in[1];
    const float* b1       = (const float*)d_in[2];
    const float* ln_g     = (const float*)d_in[3];
    const float* ln_b     = (const float*)d_in[4];
    const float* in_proj  = (const float*)d_in[5];
    const float* cw_f     = (const float*)d_in[6];
    const float* cb_f     = (const float*)d_in[7];
    const float* xp_f     = (const float*)d_in[8];
    const float* dtw_f    = (const float*)d_in[9];
    const float* dtb_f    = (const float*)d_in[10];
    const float* Al_f     = (const float*)d_in[11];
    const float* Dp_f     = (const float*)d_in[12];
    const float* cw_b     = (const float*)d_in[13];
    const float* cb_b     = (const float*)d_in[14];
    const float* xp_b     = (const float*)d_in[15];
    const float* dtw_b    = (const float*)d_in[16];
    const float* dtb_b    = (const float*)d_in[17];
    const float* Al_b     = (const float*)d_in[18];
    const float* Dp_b     = (const float*)d_in[19];
    const float* norm_g   = (const float*)d_in[20];
    const float* norm_b   = (const float*)d_in[21];
    const float* Wout     = (const float*)d_in[22];
    const float* w2       = (const float*)d_in[23];
    const float* b2       = (const float*)d_in[24];

    kmax<<<NROWS * NCHUNK, 256, 0, stream>>>(x);
    ktail<<<B_SZ * 2, 1024, 0, stream>>>(w1, b1, ln_g, ln_b, in_proj,
                                         cw_f, cb_f, xp_f, dtw_f, dtb_f, Al_f, Dp_f,
                                         cw_b, cb_b, xp_b, dtw_b, dtb_b, Al_b, Dp_b,
                                         norm_g, norm_b, Wout, w2, b2, (float*)d_out);
}